// Round 1
// baseline (177.029 us; speedup 1.0000x reference)
//
#include <hip/hip_runtime.h>
#include <hip/hip_bf16.h>

typedef __attribute__((ext_vector_type(8))) short short8;
typedef __attribute__((ext_vector_type(4))) float f32x4;

#define SCALE 0.31622776601683794f  // 1/sqrt(10)

static __device__ __forceinline__ void gload16(const void* g, void* l) {
  __builtin_amdgcn_global_load_lds((const __attribute__((address_space(1))) void*)g,
                                   (__attribute__((address_space(3))) void*)l, 16, 0, 0);
}

// ---------------- kernel 1: convert q,k,v fp32 -> bf16 ----------------
// 3 * 4M elements, 8 per thread, grid exactly covers.
__global__ void k_cvt_qkv(const float* __restrict__ q, const float* __restrict__ kk,
                          const float* __restrict__ v, __hip_bfloat16* __restrict__ xb) {
  const size_t i = ((size_t)blockIdx.x * 256 + threadIdx.x) * 8;
  const int t = (int)(i >> 22);                 // 4194304 elements per tensor
  const float* src = (t == 0) ? q : (t == 1) ? kk : v;
  const size_t off = i & 4194303u;
  float4 f0 = *(const float4*)(src + off);
  float4 f1 = *(const float4*)(src + off + 4);
  union { short8 s; __hip_bfloat16 h[8]; } u;
  u.h[0] = __float2bfloat16(f0.x); u.h[1] = __float2bfloat16(f0.y);
  u.h[2] = __float2bfloat16(f0.z); u.h[3] = __float2bfloat16(f0.w);
  u.h[4] = __float2bfloat16(f1.x); u.h[5] = __float2bfloat16(f1.y);
  u.h[6] = __float2bfloat16(f1.z); u.h[7] = __float2bfloat16(f1.w);
  *(short8*)((char*)xb + i * 2) = u.s;
}

// ---------------- kernel 2: convert + transpose weights ----------------
// Wt[z][n][k] = W[z][k][n] as bf16.  grid (16,16,3), block 256.
__global__ void k_cvt_w(const float* __restrict__ Wq, const float* __restrict__ Wk,
                        const float* __restrict__ Wv, __hip_bfloat16* __restrict__ wt) {
  __shared__ float T[64][65];
  const int z = blockIdx.z;
  const float* W = (z == 0) ? Wq : (z == 1) ? Wk : Wv;
  __hip_bfloat16* Wd = wt + (size_t)z * 1048576;
  const int n0 = blockIdx.x * 64, k0 = blockIdx.y * 64;
  const int tx = threadIdx.x & 63, ty = threadIdx.x >> 6;
#pragma unroll
  for (int r = 0; r < 16; ++r)
    T[ty + r * 4][tx] = W[(size_t)(k0 + ty + r * 4) * 1024 + n0 + tx];
  __syncthreads();
#pragma unroll
  for (int r = 0; r < 16; ++r)
    Wd[(size_t)(n0 + ty + r * 4) * 1024 + k0 + tx] = __float2bfloat16(T[tx][ty + r * 4]);
}

// ---------------- kernel 3: projection GEMM ----------------
// O[t] = Xb[t] @ W[t] + b[t];  out layouts: Q,K -> [b,h,s,64]; V -> [b,h,64,s] (transposed)
// 128x128 tile, BK=32, 4 waves, 16x16x32 bf16 MFMA, global_load_lds(16B), 16B-granule XOR swizzle.
__global__ __launch_bounds__(256) void k_proj(
    const __hip_bfloat16* __restrict__ xb, const __hip_bfloat16* __restrict__ wt,
    const float* __restrict__ bq, const float* __restrict__ bk, const float* __restrict__ bv,
    __hip_bfloat16* __restrict__ Qb, __hip_bfloat16* __restrict__ Kb,
    __hip_bfloat16* __restrict__ Vt) {
  __shared__ char As[8192];   // [128 rows][32 bf16] = 64B rows
  __shared__ char Bs[8192];
  const int t = blockIdx.z;
  const char* X = (const char*)(xb + (size_t)t * 4194304);
  const char* W = (const char*)(wt + (size_t)t * 1048576);
  const float* bias = (t == 0) ? bq : (t == 1) ? bk : bv;
  const int m0 = blockIdx.y * 128, n0 = blockIdx.x * 128;
  const int tid = threadIdx.x, w = tid >> 6, lane = tid & 63;
  const int r_in = lane >> 2;                                 // row within 16-row chunk
  const int cswz = (((lane & 3) ^ ((lane >> 2) & 3)) << 4);   // pre-swizzled global 16B slot
  const int wm = (w >> 1) * 64, wn = (w & 1) * 64;
  f32x4 acc[4][4];
#pragma unroll
  for (int i = 0; i < 4; ++i)
#pragma unroll
    for (int j = 0; j < 4; ++j) acc[i][j] = (f32x4){0.f, 0.f, 0.f, 0.f};

  for (int k0 = 0; k0 < 1024; k0 += 32) {
    __syncthreads();
#pragma unroll
    for (int j = 0; j < 2; ++j) {
      const int ch = w * 2 + j;
      gload16(X + (size_t)(m0 + ch * 16 + r_in) * 2048 + k0 * 2 + cswz, As + ch * 1024);
      gload16(W + (size_t)(n0 + ch * 16 + r_in) * 2048 + k0 * 2 + cswz, Bs + ch * 1024);
    }
    __syncthreads();
    short8 af[4], bf_[4];
#pragma unroll
    for (int mt = 0; mt < 4; ++mt) {
      const int row = wm + mt * 16 + (lane & 15);
      af[mt] = *(const short8*)(As + row * 64 + (((lane >> 4) * 16) ^ ((row & 3) << 4)));
    }
#pragma unroll
    for (int nt = 0; nt < 4; ++nt) {
      const int row = wn + nt * 16 + (lane & 15);
      bf_[nt] = *(const short8*)(Bs + row * 64 + (((lane >> 4) * 16) ^ ((row & 3) << 4)));
    }
#pragma unroll
    for (int mt = 0; mt < 4; ++mt)
#pragma unroll
      for (int nt = 0; nt < 4; ++nt)
        acc[mt][nt] = __builtin_amdgcn_mfma_f32_16x16x32_bf16(af[mt], bf_[nt], acc[mt][nt], 0, 0, 0);
  }

  // epilogue: +bias, bf16, scatter to attention layouts
  float bv4[4];
#pragma unroll
  for (int nt = 0; nt < 4; ++nt) bv4[nt] = bias[n0 + wn + nt * 16 + (lane & 15)];
#pragma unroll
  for (int mt = 0; mt < 4; ++mt) {
#pragma unroll
    for (int nt = 0; nt < 4; ++nt) {
      const int feat = n0 + wn + nt * 16 + (lane & 15);
      const int h = feat >> 6, d = feat & 63;
#pragma unroll
      for (int r = 0; r < 4; ++r) {
        const int token = m0 + wm + mt * 16 + (lane >> 4) * 4 + r;
        const int b = token >> 11, s = token & 2047;
        const float val = acc[mt][nt][r] + bv4[nt];
        const __hip_bfloat16 hb = __float2bfloat16(val);
        if (t == 0)      Qb[((size_t)(b * 16 + h) * 2048 + s) * 64 + d] = hb;
        else if (t == 1) Kb[((size_t)(b * 16 + h) * 2048 + s) * 64 + d] = hb;
        else             Vt[((size_t)(b * 16 + h) * 64 + d) * 2048 + s] = hb;
      }
    }
  }
}

// ---------------- kernel 4: flash attention ----------------
// grid (S/64, B*H), block 256 (4 waves x 16 q-rows). KVBLK=64.
// K,Vt staged via global_load_lds with pre-swizzled source; reads XOR-swizzled (row&7)<<4.
__global__ __launch_bounds__(256) void k_attn(
    const __hip_bfloat16* __restrict__ Qb, const __hip_bfloat16* __restrict__ Kb,
    const __hip_bfloat16* __restrict__ Vt, const int* __restrict__ mask,
    float* __restrict__ out) {
  __shared__ char Ks[8192];                 // [64 keys][64 bf16] 128B rows, swizzled
  __shared__ char Vs[8192];                 // [64 d][64 keys bf16] 128B rows, swizzled
  __shared__ __hip_bfloat16 Pl[4][16][72];  // per-wave P tile, 144B rows (16B aligned)
  const int qb = blockIdx.x, bh = blockIdx.y;
  const int b = bh >> 4, h = bh & 15;
  const int tid = threadIdx.x, w = tid >> 6, lane = tid & 63;
  const char* Qc = (const char*)(Qb + (size_t)bh * 131072);
  const char* Kc = (const char*)(Kb + (size_t)bh * 131072);
  const char* Vc = (const char*)(Vt + (size_t)bh * 131072);
  const int* mp = mask + b * 2048;

  // Q A-fragments held in registers
  short8 aq[2];
  const int arow = qb * 64 + w * 16 + (lane & 15);
#pragma unroll
  for (int kc = 0; kc < 2; ++kc)
    aq[kc] = *(const short8*)(Qc + (size_t)arow * 128 + kc * 64 + (lane >> 4) * 16);

  f32x4 oacc[4];
#pragma unroll
  for (int i = 0; i < 4; ++i) oacc[i] = (f32x4){0.f, 0.f, 0.f, 0.f};
  float mrow[4] = {-__builtin_inff(), -__builtin_inff(), -__builtin_inff(), -__builtin_inff()};
  float lrow[4] = {0.f, 0.f, 0.f, 0.f};

  const int l8 = lane >> 3, l7 = lane & 7;
  const int vswz = ((l7 ^ l8) << 4);        // pre-swizzled global 16B slot within 128B row

  for (int kt = 0; kt < 32; ++kt) {
    __syncthreads();
#pragma unroll
    for (int j = 0; j < 2; ++j) {
      const int ch = w * 2 + j;
      gload16(Kc + (size_t)(kt * 64 + ch * 8 + l8) * 128 + vswz, Ks + ch * 1024);
      gload16(Vc + (size_t)(ch * 8 + l8) * 4096 + kt * 128 + vswz, Vs + ch * 1024);
    }
    __syncthreads();

    // QK^T -> scores (C: col=key=lane&15, row=q=(lane>>4)*4+r)
    float p[4][4];
#pragma unroll
    for (int nt = 0; nt < 4; ++nt) {
      f32x4 s = (f32x4){0.f, 0.f, 0.f, 0.f};
      const int key = nt * 16 + (lane & 15);
#pragma unroll
      for (int kc = 0; kc < 2; ++kc) {
        const short8 bkf = *(const short8*)(Ks + key * 128 +
                            ((kc * 64 + (lane >> 4) * 16) ^ ((key & 7) << 4)));
        s = __builtin_amdgcn_mfma_f32_16x16x32_bf16(aq[kc], bkf, s, 0, 0, 0);
      }
      const float biasv = (mp[kt * 64 + key] == 0) ? -1e9f : 0.0f;
#pragma unroll
      for (int r = 0; r < 4; ++r) p[nt][r] = s[r] * SCALE + biasv;
    }

    // online softmax per q row
    float corr[4];
#pragma unroll
    for (int r = 0; r < 4; ++r) {
      float tmax = fmaxf(fmaxf(p[0][r], p[1][r]), fmaxf(p[2][r], p[3][r]));
      tmax = fmaxf(tmax, __shfl_xor(tmax, 1));
      tmax = fmaxf(tmax, __shfl_xor(tmax, 2));
      tmax = fmaxf(tmax, __shfl_xor(tmax, 4));
      tmax = fmaxf(tmax, __shfl_xor(tmax, 8));
      const float mnew = fmaxf(mrow[r], tmax);
      corr[r] = __expf(mrow[r] - mnew);
      mrow[r] = mnew;
      float ps = 0.f;
#pragma unroll
      for (int nt = 0; nt < 4; ++nt) { p[nt][r] = __expf(p[nt][r] - mnew); ps += p[nt][r]; }
      ps += __shfl_xor(ps, 1);
      ps += __shfl_xor(ps, 2);
      ps += __shfl_xor(ps, 4);
      ps += __shfl_xor(ps, 8);
      lrow[r] = lrow[r] * corr[r] + ps;
    }
#pragma unroll
    for (int dt = 0; dt < 4; ++dt) {
      f32x4 o = oacc[dt];
#pragma unroll
      for (int r = 0; r < 4; ++r) o[r] *= corr[r];
      oacc[dt] = o;
    }

    // P -> LDS (re-layout to A-fragment), then PV
#pragma unroll
    for (int nt = 0; nt < 4; ++nt)
#pragma unroll
      for (int r = 0; r < 4; ++r)
        Pl[w][(lane >> 4) * 4 + r][nt * 16 + (lane & 15)] = __float2bfloat16(p[nt][r]);

    short8 pa[2];
#pragma unroll
    for (int kc = 0; kc < 2; ++kc)
      pa[kc] = *(const short8*)(&Pl[w][lane & 15][kc * 32 + (lane >> 4) * 8]);

#pragma unroll
    for (int dt = 0; dt < 4; ++dt) {
      const int d = dt * 16 + (lane & 15);
      f32x4 o = oacc[dt];
#pragma unroll
      for (int kc = 0; kc < 2; ++kc) {
        const short8 bvf = *(const short8*)(Vs + d * 128 +
                            ((kc * 64 + (lane >> 4) * 16) ^ ((d & 7) << 4)));
        o = __builtin_amdgcn_mfma_f32_16x16x32_bf16(pa[kc], bvf, o, 0, 0, 0);
      }
      oacc[dt] = o;
    }
  }

  // epilogue: divide by l, store fp32
#pragma unroll
  for (int dt = 0; dt < 4; ++dt) {
#pragma unroll
    for (int r = 0; r < 4; ++r) {
      const int s = qb * 64 + w * 16 + (lane >> 4) * 4 + r;
      const float val = oacc[dt][r] / lrow[r];
      out[((size_t)(b * 2048 + s)) * 1024 + h * 64 + dt * 16 + (lane & 15)] = val;
    }
  }
}

// ---------------- launcher ----------------
extern "C" void kernel_launch(void* const* d_in, const int* in_sizes, int n_in,
                              void* d_out, int out_size, void* d_ws, size_t ws_size,
                              hipStream_t stream) {
  const float* q   = (const float*)d_in[0];
  const float* k   = (const float*)d_in[1];
  const float* v   = (const float*)d_in[2];
  const int* mask  = (const int*)d_in[3];
  const float* Wq  = (const float*)d_in[4];
  const float* bq  = (const float*)d_in[5];
  const float* Wk  = (const float*)d_in[6];
  const float* bk  = (const float*)d_in[7];
  const float* Wv  = (const float*)d_in[8];
  const float* bv  = (const float*)d_in[9];
  float* out = (float*)d_out;
  char* ws = (char*)d_ws;
  // workspace layout (bytes): Xb 0..25165824, Wt ..31457280, Qb ..39845888,
  // Kb ..48234496, Vt ..56623104  (total ~54MB)
  __hip_bfloat16* Xb = (__hip_bfloat16*)(ws);
  __hip_bfloat16* Wt = (__hip_bfloat16*)(ws + 25165824);
  __hip_bfloat16* Qb = (__hip_bfloat16*)(ws + 31457280);
  __hip_bfloat16* Kb = (__hip_bfloat16*)(ws + 39845888);
  __hip_bfloat16* Vt = (__hip_bfloat16*)(ws + 48234496);

  k_cvt_qkv<<<dim3(6144), dim3(256), 0, stream>>>(q, k, v, Xb);
  k_cvt_w<<<dim3(16, 16, 3), dim3(256), 0, stream>>>(Wq, Wk, Wv, Wt);
  k_proj<<<dim3(8, 32, 3), dim3(256), 0, stream>>>(Xb, Wt, bq, bk, bv, Qb, Kb, Vt);
  k_attn<<<dim3(32, 32), dim3(256), 0, stream>>>(Qb, Kb, Vt, mask, out);
}

// Round 2
// 138.398 us; speedup vs baseline: 1.2791x; 1.2791x over previous
//
#include <hip/hip_runtime.h>
#include <hip/hip_bf16.h>

typedef __attribute__((ext_vector_type(8))) short short8;
typedef __attribute__((ext_vector_type(4))) short short4v;
typedef __attribute__((ext_vector_type(4))) float f32x4;

#define SCALE 0.31622776601683794f          // 1/sqrt(10)
#define SC_L2E 0.4561727848849353f          // SCALE * log2(e)

#if __has_builtin(__builtin_amdgcn_exp2f)
#define EXP2F __builtin_amdgcn_exp2f
#else
#define EXP2F exp2f
#endif

static __device__ __forceinline__ f32x4 mfma16(short4v a, short4v b, f32x4 c) {
#if __has_builtin(__builtin_amdgcn_mfma_f32_16x16x16bf16_1k)
  return __builtin_amdgcn_mfma_f32_16x16x16bf16_1k(a, b, c, 0, 0, 0);
#else
  asm("v_mfma_f32_16x16x16_bf16 %0, %1, %2, %0" : "+v"(c) : "v"(a), "v"(b));
  return c;
#endif
}

static __device__ __forceinline__ void gload16(const void* g, void* l) {
  __builtin_amdgcn_global_load_lds((const __attribute__((address_space(1))) void*)g,
                                   (__attribute__((address_space(3))) void*)l, 16, 0, 0);
}

// ---------------- kernel 1: convert q,k,v fp32 -> bf16 ----------------
__global__ void k_cvt_qkv(const float* __restrict__ q, const float* __restrict__ kk,
                          const float* __restrict__ v, __hip_bfloat16* __restrict__ xb) {
  const size_t i = ((size_t)blockIdx.x * 256 + threadIdx.x) * 8;
  const int t = (int)(i >> 22);                 // 4194304 elements per tensor
  const float* src = (t == 0) ? q : (t == 1) ? kk : v;
  const size_t off = i & 4194303u;
  float4 f0 = *(const float4*)(src + off);
  float4 f1 = *(const float4*)(src + off + 4);
  union { short8 s; __hip_bfloat16 h[8]; } u;
  u.h[0] = __float2bfloat16(f0.x); u.h[1] = __float2bfloat16(f0.y);
  u.h[2] = __float2bfloat16(f0.z); u.h[3] = __float2bfloat16(f0.w);
  u.h[4] = __float2bfloat16(f1.x); u.h[5] = __float2bfloat16(f1.y);
  u.h[6] = __float2bfloat16(f1.z); u.h[7] = __float2bfloat16(f1.w);
  *(short8*)((char*)xb + i * 2) = u.s;
}

// ---------------- kernel 2: convert + transpose weights ----------------
__global__ void k_cvt_w(const float* __restrict__ Wq, const float* __restrict__ Wk,
                        const float* __restrict__ Wv, __hip_bfloat16* __restrict__ wt) {
  __shared__ float T[64][65];
  const int z = blockIdx.z;
  const float* W = (z == 0) ? Wq : (z == 1) ? Wk : Wv;
  __hip_bfloat16* Wd = wt + (size_t)z * 1048576;
  const int n0 = blockIdx.x * 64, k0 = blockIdx.y * 64;
  const int tx = threadIdx.x & 63, ty = threadIdx.x >> 6;
#pragma unroll
  for (int r = 0; r < 16; ++r)
    T[ty + r * 4][tx] = W[(size_t)(k0 + ty + r * 4) * 1024 + n0 + tx];
  __syncthreads();
#pragma unroll
  for (int r = 0; r < 16; ++r)
    Wd[(size_t)(n0 + ty + r * 4) * 1024 + k0 + tx] = __float2bfloat16(T[tx][ty + r * 4]);
}

// ---------------- kernel 3: projection GEMM ----------------
__global__ __launch_bounds__(256) void k_proj(
    const __hip_bfloat16* __restrict__ xb, const __hip_bfloat16* __restrict__ wt,
    const float* __restrict__ bq, const float* __restrict__ bk, const float* __restrict__ bv,
    __hip_bfloat16* __restrict__ Qb, __hip_bfloat16* __restrict__ Kb,
    __hip_bfloat16* __restrict__ Vt) {
  __shared__ char As[8192];   // [128 rows][32 bf16] = 64B rows
  __shared__ char Bs[8192];
  const int t = blockIdx.z;
  const char* X = (const char*)(xb + (size_t)t * 4194304);
  const char* W = (const char*)(wt + (size_t)t * 1048576);
  const float* bias = (t == 0) ? bq : (t == 1) ? bk : bv;
  const int m0 = blockIdx.y * 128, n0 = blockIdx.x * 128;
  const int tid = threadIdx.x, w = tid >> 6, lane = tid & 63;
  const int r_in = lane >> 2;
  const int cswz = (((lane & 3) ^ ((lane >> 2) & 3)) << 4);
  const int wm = (w >> 1) * 64, wn = (w & 1) * 64;
  f32x4 acc[4][4];
#pragma unroll
  for (int i = 0; i < 4; ++i)
#pragma unroll
    for (int j = 0; j < 4; ++j) acc[i][j] = (f32x4){0.f, 0.f, 0.f, 0.f};

  for (int k0 = 0; k0 < 1024; k0 += 32) {
    __syncthreads();
#pragma unroll
    for (int j = 0; j < 2; ++j) {
      const int ch = w * 2 + j;
      gload16(X + (size_t)(m0 + ch * 16 + r_in) * 2048 + k0 * 2 + cswz, As + ch * 1024);
      gload16(W + (size_t)(n0 + ch * 16 + r_in) * 2048 + k0 * 2 + cswz, Bs + ch * 1024);
    }
    __syncthreads();
    short8 af[4], bf_[4];
#pragma unroll
    for (int mt = 0; mt < 4; ++mt) {
      const int row = wm + mt * 16 + (lane & 15);
      af[mt] = *(const short8*)(As + row * 64 + (((lane >> 4) * 16) ^ ((row & 3) << 4)));
    }
#pragma unroll
    for (int nt = 0; nt < 4; ++nt) {
      const int row = wn + nt * 16 + (lane & 15);
      bf_[nt] = *(const short8*)(Bs + row * 64 + (((lane >> 4) * 16) ^ ((row & 3) << 4)));
    }
#pragma unroll
    for (int mt = 0; mt < 4; ++mt)
#pragma unroll
      for (int nt = 0; nt < 4; ++nt)
        acc[mt][nt] = __builtin_amdgcn_mfma_f32_16x16x32_bf16(af[mt], bf_[nt], acc[mt][nt], 0, 0, 0);
  }

  float bv4[4];
#pragma unroll
  for (int nt = 0; nt < 4; ++nt) bv4[nt] = bias[n0 + wn + nt * 16 + (lane & 15)];
#pragma unroll
  for (int mt = 0; mt < 4; ++mt) {
#pragma unroll
    for (int nt = 0; nt < 4; ++nt) {
      const int feat = n0 + wn + nt * 16 + (lane & 15);
      const int h = feat >> 6, d = feat & 63;
#pragma unroll
      for (int r = 0; r < 4; ++r) {
        const int token = m0 + wm + mt * 16 + (lane >> 4) * 4 + r;
        const int b = token >> 11, s = token & 2047;
        const float val = acc[mt][nt][r] + bv4[nt];
        const __hip_bfloat16 hb = __float2bfloat16(val);
        if (t == 0)      Qb[((size_t)(b * 16 + h) * 2048 + s) * 64 + d] = hb;
        else if (t == 1) Kb[((size_t)(b * 16 + h) * 2048 + s) * 64 + d] = hb;
        else             Vt[((size_t)(b * 16 + h) * 64 + d) * 2048 + s] = hb;
      }
    }
  }
}

// ---------------- kernel 4: flash attention (swapped QK^T, in-register P) --------
// grid (S/64, B*H), block 256 (4 waves, one 16-q tile each). KVBLK=64.
// Per lane: q = lane&15 fixed -> softmax state lane-local.
// QK^T: s[nt] = mfma32(Kfrag, Qfrag) -> S^T[key=nt*16+g*4+r][q].
// PV:   O^T[d][q] += mfma16(V^T-frag, P^T-frag) with P^T straight from registers.
__global__ __launch_bounds__(256, 4) void k_attn(
    const __hip_bfloat16* __restrict__ Qb, const __hip_bfloat16* __restrict__ Kb,
    const __hip_bfloat16* __restrict__ Vt, const int* __restrict__ mask,
    float* __restrict__ out) {
  __shared__ char Ks[2][8192];              // [64 keys][64 bf16] 128B rows, swizzled
  __shared__ char Vs[2][8192];              // [64 d][64 keys bf16] 128B rows, swizzled
  const int qb = blockIdx.x, bh = blockIdx.y;
  const int b = bh >> 4, h = bh & 15;
  const int tid = threadIdx.x, w = tid >> 6, lane = tid & 63;
  const int g = lane >> 4;                  // lane group 0..3
  const char* Qc = (const char*)(Qb + (size_t)bh * 131072);
  const char* Kc = (const char*)(Kb + (size_t)bh * 131072);
  const char* Vc = (const char*)(Vt + (size_t)bh * 131072);
  const int* mp = mask + b * 2048;

  const int l8 = lane >> 3, l7 = lane & 7;
  const int vswz = ((l7 ^ l8) << 4);        // pre-swizzled global 16B slot in 128B row

  // Q B-fragments in registers: lane holds Q[q=lane&15][k = kc*32 + g*8 .. +7]
  short8 aq[2];
  const int arow = qb * 64 + w * 16 + (lane & 15);
#pragma unroll
  for (int kc = 0; kc < 2; ++kc)
    aq[kc] = *(const short8*)(Qc + (size_t)arow * 128 + kc * 64 + g * 16);

  f32x4 oaccT[4];                           // O^T: row d=dt*16+g*4+r, col q=lane&15
#pragma unroll
  for (int i = 0; i < 4; ++i) oaccT[i] = (f32x4){0.f, 0.f, 0.f, 0.f};
  float m2 = -__builtin_inff();             // running max, exp2 domain, per-lane q
  float l = 0.f;

  // prologue: stage tile 0 into buffer 0
#pragma unroll
  for (int j = 0; j < 2; ++j) {
    const int ch = w * 2 + j;
    gload16(Kc + (size_t)(ch * 8 + l8) * 128 + vswz, Ks[0] + ch * 1024);
    gload16(Vc + (size_t)(ch * 8 + l8) * 4096 + vswz, Vs[0] + ch * 1024);
  }
  __syncthreads();

  int cur = 0;
  for (int kt = 0; kt < 32; ++kt) {
    // mask loads FIRST (so their wait leaves the prefetch in flight)
    int4 mv[4];
#pragma unroll
    for (int nt = 0; nt < 4; ++nt)
      mv[nt] = *(const int4*)(mp + kt * 64 + nt * 16 + g * 4);

    // prefetch next tile into buf^1
    if (kt < 31) {
#pragma unroll
      for (int j = 0; j < 2; ++j) {
        const int ch = w * 2 + j;
        gload16(Kc + (size_t)((kt + 1) * 64 + ch * 8 + l8) * 128 + vswz, Ks[cur ^ 1] + ch * 1024);
        gload16(Vc + (size_t)(ch * 8 + l8) * 4096 + (kt + 1) * 128 + vswz, Vs[cur ^ 1] + ch * 1024);
      }
    }

    const char* Kl = Ks[cur];
    const char* Vl = Vs[cur];

    // swapped QK^T
    f32x4 s_[4];
    __builtin_amdgcn_s_setprio(1);
#pragma unroll
    for (int nt = 0; nt < 4; ++nt) {
      s_[nt] = (f32x4){0.f, 0.f, 0.f, 0.f};
      const int key = nt * 16 + (lane & 15);
#pragma unroll
      for (int kc = 0; kc < 2; ++kc) {
        const short8 kf = *(const short8*)(Kl + key * 128 +
                           ((kc * 64 + g * 16) ^ ((key & 7) << 4)));
        s_[nt] = __builtin_amdgcn_mfma_f32_16x16x32_bf16(kf, aq[kc], s_[nt], 0, 0, 0);
      }
    }
    __builtin_amdgcn_s_setprio(0);

    // scores -> exp2 domain, masked keys pre-biased to -1e30 (excluded from max)
    float xl2[4][4];
#pragma unroll
    for (int nt = 0; nt < 4; ++nt) {
      xl2[nt][0] = mv[nt].x ? s_[nt][0] * SC_L2E : -1e30f;
      xl2[nt][1] = mv[nt].y ? s_[nt][1] * SC_L2E : -1e30f;
      xl2[nt][2] = mv[nt].z ? s_[nt][2] * SC_L2E : -1e30f;
      xl2[nt][3] = mv[nt].w ? s_[nt][3] * SC_L2E : -1e30f;
    }

    // lane-local tile max over 16 + 2-shfl reduce across the 4 lane copies of q
    float tmax = xl2[0][0];
#pragma unroll
    for (int nt = 0; nt < 4; ++nt)
#pragma unroll
      for (int r = 0; r < 4; ++r) tmax = fmaxf(tmax, xl2[nt][r]);
    tmax = fmaxf(tmax, __shfl_xor(tmax, 16));
    tmax = fmaxf(tmax, __shfl_xor(tmax, 32));

    // defer-max (T13): rescale only when max grew past threshold
    if (!__all(tmax <= m2 + 8.0f)) {
      const float mn = fmaxf(fmaxf(m2, tmax), -1e9f);
      const float corr = EXP2F(m2 - mn);    // m2=-inf on first tile -> corr=0
      m2 = mn;
      l *= corr;
#pragma unroll
      for (int dt = 0; dt < 4; ++dt) {
#pragma unroll
        for (int r = 0; r < 4; ++r) oaccT[dt][r] *= corr;
      }
    }

    // P = exp2(x - m2); row-sum (lane-local + 2 shfl); pack to bf16 P^T fragments
    float ps = 0.f;
    short4v pb[4];
#pragma unroll
    for (int nt = 0; nt < 4; ++nt) {
      union { short4v s4; __hip_bfloat16 hh[4]; } pu;
#pragma unroll
      for (int r = 0; r < 4; ++r) {
        const float e = EXP2F(xl2[nt][r] - m2);
        ps += e;
        pu.hh[r] = __float2bfloat16(e);
      }
      pb[nt] = pu.s4;
    }
    ps += __shfl_xor(ps, 16);
    ps += __shfl_xor(ps, 32);
    l += ps;

    // PV: O^T[d][q] via 16x16x16 MFMA, A = V^T chunk from LDS, B = P^T from regs
    __builtin_amdgcn_s_setprio(1);
#pragma unroll
    for (int dt = 0; dt < 4; ++dt) {
      f32x4 o = oaccT[dt];
      const int vrow = dt * 16 + (lane & 15);
#pragma unroll
      for (int nt = 0; nt < 4; ++nt) {
        const short4v vf = *(const short4v*)(Vl + vrow * 128 +
                            ((nt * 32 + g * 8) ^ ((vrow & 7) << 4)));
        o = mfma16(vf, pb[nt], o);
      }
      oaccT[dt] = o;
    }
    __builtin_amdgcn_s_setprio(0);

    __syncthreads();                        // drains prefetch; buf^1 ready
    cur ^= 1;
  }

  // epilogue: O^T rows are d -> contiguous float4 per dt for this lane's q row
  const float rl = 1.0f / l;
  const int q = qb * 64 + w * 16 + (lane & 15);
  float* orow = out + ((size_t)(b * 2048 + q)) * 1024 + h * 64;
#pragma unroll
  for (int dt = 0; dt < 4; ++dt) {
    float4 st;
    st.x = oaccT[dt][0] * rl; st.y = oaccT[dt][1] * rl;
    st.z = oaccT[dt][2] * rl; st.w = oaccT[dt][3] * rl;
    *(float4*)(orow + dt * 16 + g * 4) = st;
  }
}

// ---------------- launcher ----------------
extern "C" void kernel_launch(void* const* d_in, const int* in_sizes, int n_in,
                              void* d_out, int out_size, void* d_ws, size_t ws_size,
                              hipStream_t stream) {
  const float* q   = (const float*)d_in[0];
  const float* k   = (const float*)d_in[1];
  const float* v   = (const float*)d_in[2];
  const int* mask  = (const int*)d_in[3];
  const float* Wq  = (const float*)d_in[4];
  const float* bq  = (const float*)d_in[5];
  const float* Wk  = (const float*)d_in[6];
  const float* bk  = (const float*)d_in[7];
  const float* Wv  = (const float*)d_in[8];
  const float* bv  = (const float*)d_in[9];
  float* out = (float*)d_out;
  char* ws = (char*)d_ws;
  __hip_bfloat16* Xb = (__hip_bfloat16*)(ws);
  __hip_bfloat16* Wt = (__hip_bfloat16*)(ws + 25165824);
  __hip_bfloat16* Qb = (__hip_bfloat16*)(ws + 31457280);
  __hip_bfloat16* Kb = (__hip_bfloat16*)(ws + 39845888);
  __hip_bfloat16* Vt = (__hip_bfloat16*)(ws + 48234496);

  k_cvt_qkv<<<dim3(6144), dim3(256), 0, stream>>>(q, k, v, Xb);
  k_cvt_w<<<dim3(16, 16, 3), dim3(256), 0, stream>>>(Wq, Wk, Wv, Wt);
  k_proj<<<dim3(8, 32, 3), dim3(256), 0, stream>>>(Xb, Wt, bq, bk, bv, Qb, Kb, Vt);
  k_attn<<<dim3(32, 32), dim3(256), 0, stream>>>(Qb, Kb, Vt, mask, out);
}